// Round 6
// baseline (547.952 us; speedup 1.0000x reference)
//
#include <hip/hip_runtime.h>
#include <math.h>

#define NB 2
#define CDIM 512
#define NT 4096
#define LOG2E 1.44269504088896f
#define SHIFT 20.0f

typedef unsigned short u16;
typedef __attribute__((ext_vector_type(8))) short short8;
typedef __attribute__((ext_vector_type(4))) float f32x4;

union U8 { u16 v[8]; uint4 u4; };
union U4 { u16 v[4]; uint2 u2; };
union US8 { uint4 u4; short8 s8; };

__device__ __forceinline__ u16 f2bf(float f) {
    union { float f; unsigned u; } v; v.f = f;
    unsigned r = (v.u + 0x7fffu + ((v.u >> 16) & 1u)) >> 16;
    return (u16)r;
}
__device__ __forceinline__ float bf2f(u16 b) {
    union { float f; unsigned u; } v; v.u = ((unsigned)b) << 16; return v.f;
}
__device__ __forceinline__ float fexp2(float x) {
#if __has_builtin(__builtin_amdgcn_exp2f)
    return __builtin_amdgcn_exp2f(x);
#else
    return exp2f(x);
#endif
}
__device__ __forceinline__ float flog2(float x) {
#if __has_builtin(__builtin_amdgcn_logf)
    return __builtin_amdgcn_logf(x);
#else
    return log2f(x);
#endif
}

// ---------------- weight convert: W1=[Wb*log2e; Wc; alpha*Wd] bf16, W2f=beta*Wd bf16 ----------------
__global__ __launch_bounds__(256) void k_convW(
    const float* __restrict__ Wb, const float* __restrict__ Wc, const float* __restrict__ Wd,
    const float* __restrict__ alpha, const float* __restrict__ beta,
    u16* __restrict__ W1, u16* __restrict__ W2f)
{
    int r = blockIdx.x, t = threadIdx.x;
    const float* src; float scale; u16* dst;
    if (r < 640) {
        dst = W1 + (size_t)r * CDIM;
        if (r < 64)       { src = Wb + (size_t)r * CDIM;        scale = LOG2E; }
        else if (r < 128) { src = Wc + (size_t)(r - 64) * CDIM; scale = 1.f; }
        else              { src = Wd + (size_t)(r - 128) * CDIM; scale = alpha[0]; }
    } else {
        int rr = r - 640;
        dst = W2f + (size_t)rr * CDIM;
        src = Wd + (size_t)rr * CDIM;
        scale = beta[0];
    }
    float2 v = *(const float2*)&src[t * 2];
    unsigned p = (unsigned)f2bf(v.x * scale) | ((unsigned)f2bf(v.y * scale) << 16);
    *(unsigned*)&dst[t * 2] = p;
}

// ---------------- x [b][c][n] fp32 -> xT [b][n][c] bf16 (64x64 tiles via LDS) ----------------
__global__ __launch_bounds__(256) void k_prep(
    const float* __restrict__ x1, const float* __restrict__ x2,
    u16* __restrict__ x1T, u16* __restrict__ x2T)
{
    __shared__ float Lt[64][65];
    int t = threadIdx.x;
    int c0 = blockIdx.x * 64, n0 = blockIdx.y * 64;
    int which = blockIdx.z & 1, batch = blockIdx.z >> 1;
    const float* src = (which ? x2 : x1) + (size_t)batch * CDIM * NT;
    u16* dst = (which ? x2T : x1T) + (size_t)batch * NT * CDIM;
    #pragma unroll
    for (int p = 0; p < 4; p++) {
        int cr = p * 16 + (t >> 4), nc = (t & 15) * 4;
        float4 v = *(const float4*)&src[(size_t)(c0 + cr) * NT + n0 + nc];
        Lt[cr][nc] = v.x; Lt[cr][nc + 1] = v.y; Lt[cr][nc + 2] = v.z; Lt[cr][nc + 3] = v.w;
    }
    __syncthreads();
    #pragma unroll
    for (int p = 0; p < 2; p++) {
        int nr = p * 32 + (t >> 3), cc = (t & 7) * 8;
        U8 u;
        #pragma unroll
        for (int j = 0; j < 8; j++) u.v[j] = f2bf(Lt[cc + j][nr]);
        *(uint4*)&dst[(size_t)(n0 + nr) * CDIM + c0 + cc] = u.u4;
    }
}

// ---------------- projection GEMM (bf16 MFMA, K=512) ----------------
template<int WHICH>
__global__ __launch_bounds__(256, 2) void k_gemm(
    const u16* __restrict__ W1, const u16* __restrict__ W2f,
    const u16* __restrict__ xT,
    const float* __restrict__ bb, const float* __restrict__ bc, const float* __restrict__ bd,
    const float* __restrict__ alpha, const float* __restrict__ beta,
    u16* __restrict__ yab, u16* __restrict__ ft)
{
    __shared__ u16 Wt[128][72];
    __shared__ u16 Xt[128][72];
    int t = threadIdx.x, lane = t & 63, w = t >> 6, q = lane >> 4, l15 = lane & 15;
    int nT_ = blockIdx.x, oT = blockIdx.y, batch = blockIdx.z;
    int n0 = nT_ * 128, o0 = oT * 128;
    const u16* Wsrc = (WHICH == 1 || oT == 0) ? (W1 + (size_t)o0 * CDIM)
                                              : (W2f + (size_t)(o0 - 128) * CDIM);
    const u16* xb = xT + ((size_t)batch * NT + n0) * CDIM;
    f32x4 acc[2][8];
    #pragma unroll
    for (int a = 0; a < 2; a++)
        #pragma unroll
        for (int b = 0; b < 8; b++) { f32x4 z = {0.f,0.f,0.f,0.f}; acc[a][b] = z; }

    for (int k0 = 0; k0 < CDIM; k0 += 64) {
        if (k0) __syncthreads();
        int r = t >> 1, h = t & 1;
        #pragma unroll
        for (int u = 0; u < 4; u++) {
            *(uint4*)&Wt[r][h * 32 + u * 8] = *(const uint4*)&Wsrc[(size_t)r * CDIM + k0 + h * 32 + u * 8];
            *(uint4*)&Xt[r][h * 32 + u * 8] = *(const uint4*)&xb[(size_t)r * CDIM + k0 + h * 32 + u * 8];
        }
        __syncthreads();
        if (oT == 0) {
            short8 af[2][2];
            #pragma unroll
            for (int ot = 0; ot < 2; ot++)
                #pragma unroll
                for (int kk = 0; kk < 2; kk++)
                    af[ot][kk] = *(const short8*)&Wt[w * 32 + ot * 16 + l15][kk * 32 + q * 8];
            #pragma unroll
            for (int kk = 0; kk < 2; kk++)
                #pragma unroll
                for (int i = 0; i < 8; i++) {
                    short8 bf = *(const short8*)&Xt[i * 16 + l15][kk * 32 + q * 8];
                    #pragma unroll
                    for (int ot = 0; ot < 2; ot++)
                        acc[ot][i] = __builtin_amdgcn_mfma_f32_16x16x32_bf16(af[ot][kk], bf, acc[ot][i], 0, 0, 0);
                }
        } else {
            short8 wf[2][2];
            #pragma unroll
            for (int ct = 0; ct < 2; ct++)
                #pragma unroll
                for (int kk = 0; kk < 2; kk++)
                    wf[ct][kk] = *(const short8*)&Wt[w * 32 + ct * 16 + l15][kk * 32 + q * 8];
            #pragma unroll
            for (int kk = 0; kk < 2; kk++)
                #pragma unroll
                for (int i = 0; i < 8; i++) {
                    short8 xf = *(const short8*)&Xt[i * 16 + l15][kk * 32 + q * 8];
                    #pragma unroll
                    for (int ct = 0; ct < 2; ct++)
                        acc[ct][i] = __builtin_amdgcn_mfma_f32_16x16x32_bf16(xf, wf[ct][kk], acc[ct][i], 0, 0, 0);
                }
        }
    }

    if (oT == 0) {
        #pragma unroll
        for (int ot = 0; ot < 2; ot++)
            #pragma unroll
            for (int i = 0; i < 8; i++) {
                int obase = w * 32 + ot * 16 + q * 4;
                int n = n0 + i * 16 + l15;
                U4 u;
                #pragma unroll
                for (int r = 0; r < 4; r++) {
                    int o = obase + r;
                    float bias = (o < 64) ? bb[o] * LOG2E : bc[o - 64];
                    u.v[r] = f2bf(acc[ot][i][r] + bias);
                }
                *(uint2*)&yab[((size_t)batch * NT + n) * 128 + obase] = u.u2;
            }
    } else {
        float bscale = (WHICH == 2) ? (alpha[0] + beta[0]) : 0.f;
        #pragma unroll
        for (int ct = 0; ct < 2; ct++)
            #pragma unroll
            for (int i = 0; i < 8; i++) {
                int c = (o0 - 128) + w * 32 + ct * 16 + l15;
                int mb = n0 + i * 16 + q * 4;
                u16* dst = &ft[((size_t)batch * CDIM + c) * NT + mb];
                U4 u;
                if (WHICH == 1) {
                    #pragma unroll
                    for (int r = 0; r < 4; r++) u.v[r] = f2bf(acc[ct][i][r]);
                } else {
                    U4 old; old.u2 = *(const uint2*)dst;
                    float bias = bd[c] * bscale;
                    #pragma unroll
                    for (int r = 0; r < 4; r++) u.v[r] = f2bf(acc[ct][i][r] + bf2f(old.v[r]) + bias);
                }
                *(uint2*)dst = u.u2;
            }
    }
}

// ---------------- denominators: denom[dir][b][n] = sum_m exp2(S - SHIFT) ----------------
__global__ __launch_bounds__(256, 4) void k_denom(
    const u16* __restrict__ yab1, const u16* __restrict__ yab2,
    float* __restrict__ denom)
{
    int t = threadIdx.x, lane = t & 63, w = t >> 6, q = lane >> 4, l15 = lane & 15;
    int x = blockIdx.x & 15;
    int batch = x & 1, m8 = x >> 1;
    int n0 = (blockIdx.x >> 4) * 32;
    const u16* y1 = yab1 + (size_t)batch * NT * 128;
    const u16* y2 = yab2 + (size_t)batch * NT * 128;

    short8 a1f[2][2], a2f[2][2];
    #pragma unroll
    for (int i = 0; i < 2; i++)
        #pragma unroll
        for (int kk = 0; kk < 2; kk++) {
            a1f[i][kk] = *(const short8*)&y1[(size_t)(n0 + i * 16 + l15) * 128 + kk * 32 + q * 8];
            a2f[i][kk] = *(const short8*)&y2[(size_t)(n0 + i * 16 + l15) * 128 + kk * 32 + q * 8];
        }

    float sm[2][2] = {{0.f,0.f},{0.f,0.f}};
    for (int mc = 0; mc < 512; mc += 64) {
        int mrow = m8 * 512 + mc + w * 16 + l15;
        const u16* r1 = y1 + (size_t)mrow * 128 + 64;
        const u16* r2 = y2 + (size_t)mrow * 128 + 64;
        short8 b1k0 = *(const short8*)(r1 + q * 8);
        short8 b1k1 = *(const short8*)(r1 + 32 + q * 8);
        short8 b2k0 = *(const short8*)(r2 + q * 8);
        short8 b2k1 = *(const short8*)(r2 + 32 + q * 8);
        #pragma unroll
        for (int i = 0; i < 2; i++) {
            f32x4 z = {0.f,0.f,0.f,0.f};
            f32x4 s12 = __builtin_amdgcn_mfma_f32_16x16x32_bf16(b2k0, a1f[i][0], z, 0, 0, 0);
            s12 = __builtin_amdgcn_mfma_f32_16x16x32_bf16(b2k1, a1f[i][1], s12, 0, 0, 0);
            f32x4 s21 = __builtin_amdgcn_mfma_f32_16x16x32_bf16(b1k0, a2f[i][0], z, 0, 0, 0);
            s21 = __builtin_amdgcn_mfma_f32_16x16x32_bf16(b1k1, a2f[i][1], s21, 0, 0, 0);
            #pragma unroll
            for (int r = 0; r < 4; r++) {
                sm[0][i] += fexp2(s12[r] - SHIFT);
                sm[1][i] += fexp2(s21[r] - SHIFT);
            }
        }
    }
    #pragma unroll
    for (int d = 0; d < 2; d++)
        #pragma unroll
        for (int i = 0; i < 2; i++) {
            float v = sm[d][i];
            v += __shfl_xor(v, 16);
            v += __shfl_xor(v, 32);
            if (q == 0)
                atomicAdd(&denom[((size_t)d * NB + batch) * NT + n0 + i * 16 + l15], v);
        }
}

// ---------------- P + apply: fully wave-private, ZERO LDS / ZERO barriers ----------------
// Each wave owns (16 n) x (256 c) x (2048 m). Score D-layout (row m=q*4+r, col n=l15) is
// converted to apply B-operand layout (k m=q*8+j, col n=l15) via 8 ds_bpermute + selects.
// xcd = blk&7 fixes (batch, mh, chalf) per XCD: hot set = 1MB ft-quarter + 1MB y-b (L2-resident).
__global__ __launch_bounds__(256, 2) void k_papply(
    const u16* __restrict__ yab1, const u16* __restrict__ yab2,
    const u16* __restrict__ ft, const float* __restrict__ denom,
    float* __restrict__ out, float* __restrict__ partial)
{
    int t = threadIdx.x, lane = t & 63, w = t >> 6, q = lane >> 4, l15 = lane & 15;
    int blk = blockIdx.x;
    int batch = blk & 1, mh = (blk >> 1) & 1, ch = (blk >> 2) & 1;
    int n0 = (blk >> 3) * 64 + w * 16;
    int c0 = ch * 256;
    const u16* y1 = yab1 + (size_t)batch * NT * 128;
    const u16* y2 = yab2 + (size_t)batch * NT * 128;
    const u16* ftb = ft + ((size_t)batch * CDIM + c0) * NT;

    // loop-invariant a-fragments (B-operand: col n = l15, k = channel)
    short8 a1f[2], a2f[2];
    #pragma unroll
    for (int kk = 0; kk < 2; kk++) {
        a1f[kk] = *(const short8*)&y1[(size_t)(n0 + l15) * 128 + kk * 32 + q * 8];
        a2f[kk] = *(const short8*)&y2[(size_t)(n0 + l15) * 128 + kk * 32 + q * 8];
    }
    float ls12 = SHIFT + flog2(denom[(size_t)batch * NT + n0 + l15]);
    float ls21 = SHIFT + flog2(denom[((size_t)NB + batch) * NT + n0 + l15]);

    f32x4 o[16];
    #pragma unroll
    for (int ct = 0; ct < 16; ct++) { f32x4 z = {0.f,0.f,0.f,0.f}; o[ct] = z; }

    const int la = ((q & 1) << 5) + l15;   // source lane q' = 2*(q&1)
    const int lb = la + 16;                // source lane q' = 2*(q&1)+1
    const bool hi = q >= 2;

    const int mbeg = mh * 2048, mend = mh * 2048 + 2048;
    for (int mb = mbeg; mb < mend; mb += 32) {
        // ---- b loads: two 16-m tiles, both K-halves, both tensors (8 x b128) ----
        const u16* r1a = y1 + (size_t)(mb + l15) * 128 + 64 + q * 8;
        const u16* r1b = y1 + (size_t)(mb + 16 + l15) * 128 + 64 + q * 8;
        const u16* r2a = y2 + (size_t)(mb + l15) * 128 + 64 + q * 8;
        const u16* r2b = y2 + (size_t)(mb + 16 + l15) * 128 + 64 + q * 8;
        short8 b1t0k0 = *(const short8*)(r1a);
        short8 b1t0k1 = *(const short8*)(r1a + 32);
        short8 b1t1k0 = *(const short8*)(r1b);
        short8 b1t1k1 = *(const short8*)(r1b + 32);
        short8 b2t0k0 = *(const short8*)(r2a);
        short8 b2t0k1 = *(const short8*)(r2a + 32);
        short8 b2t1k0 = *(const short8*)(r2b);
        short8 b2t1k1 = *(const short8*)(r2b + 32);

        // ---- scores + P pack: pk[t] holds bf16 P[m = t*16 + q*4 + r][n = l15] ----
        uint2 pk[2];
        {
            f32x4 z = {0.f,0.f,0.f,0.f};
            f32x4 s12 = __builtin_amdgcn_mfma_f32_16x16x32_bf16(b2t0k0, a1f[0], z, 0, 0, 0);
            s12 = __builtin_amdgcn_mfma_f32_16x16x32_bf16(b2t0k1, a1f[1], s12, 0, 0, 0);
            f32x4 s21 = __builtin_amdgcn_mfma_f32_16x16x32_bf16(b1t0k0, a2f[0], z, 0, 0, 0);
            s21 = __builtin_amdgcn_mfma_f32_16x16x32_bf16(b1t0k1, a2f[1], s21, 0, 0, 0);
            U4 u;
            #pragma unroll
            for (int r = 0; r < 4; r++)
                u.v[r] = f2bf(fabsf(fexp2(s12[r] - ls12) - fexp2(s21[r] - ls21)));
            pk[0] = u.u2;
            s12 = __builtin_amdgcn_mfma_f32_16x16x32_bf16(b2t1k0, a1f[0], z, 0, 0, 0);
            s12 = __builtin_amdgcn_mfma_f32_16x16x32_bf16(b2t1k1, a1f[1], s12, 0, 0, 0);
            s21 = __builtin_amdgcn_mfma_f32_16x16x32_bf16(b1t1k0, a2f[0], z, 0, 0, 0);
            s21 = __builtin_amdgcn_mfma_f32_16x16x32_bf16(b1t1k1, a2f[1], s21, 0, 0, 0);
            #pragma unroll
            for (int r = 0; r < 4; r++)
                u.v[r] = f2bf(fabsf(fexp2(s12[r] - ls12) - fexp2(s21[r] - ls21)));
            pk[1] = u.u2;
        }

        // ---- lane permute: D-layout -> B-operand layout (8 bpermute + 4 selects) ----
        unsigned p00x = (unsigned)__shfl((int)pk[0].x, la);
        unsigned p00y = (unsigned)__shfl((int)pk[0].y, la);
        unsigned p01x = (unsigned)__shfl((int)pk[0].x, lb);
        unsigned p01y = (unsigned)__shfl((int)pk[0].y, lb);
        unsigned p10x = (unsigned)__shfl((int)pk[1].x, la);
        unsigned p10y = (unsigned)__shfl((int)pk[1].y, la);
        unsigned p11x = (unsigned)__shfl((int)pk[1].x, lb);
        unsigned p11y = (unsigned)__shfl((int)pk[1].y, lb);
        US8 pw;
        pw.u4 = make_uint4(hi ? p10x : p00x, hi ? p10y : p00y,
                           hi ? p11x : p01x, hi ? p11y : p01y);
        short8 pf = pw.s8;

        // ---- apply: o[ct] += ft-frag @ P  (16 x b128 loads, 16 MFMAs) ----
        #pragma unroll
        for (int ct = 0; ct < 16; ct++) {
            short8 fA = *(const short8*)&ftb[(size_t)(ct * 16 + l15) * NT + mb + q * 8];
            o[ct] = __builtin_amdgcn_mfma_f32_16x16x32_bf16(fA, pf, o[ct], 0, 0, 0);
        }
    }

    // ---- epilogue: D rows = 4 consecutive c, col n = l15 -> 64B segments per c-row ----
    float* dst = mh ? partial : out;
    #pragma unroll
    for (int ct = 0; ct < 16; ct++) {
        int c = c0 + ct * 16 + q * 4;
        #pragma unroll
        for (int r = 0; r < 4; r++)
            dst[((size_t)batch * CDIM + c + r) * NT + n0 + l15] = o[ct][r];
    }
}

// ---------------- out += partial ----------------
__global__ __launch_bounds__(256) void k_reduce(
    float* __restrict__ out, const float* __restrict__ part, int n4)
{
    int i = blockIdx.x * 256 + threadIdx.x, stride = gridDim.x * 256;
    float4* o4 = (float4*)out;
    const float4* p4 = (const float4*)part;
    for (int j = i; j < n4; j += stride) {
        float4 a = o4[j], b = p4[j];
        o4[j] = make_float4(a.x + b.x, a.y + b.y, a.z + b.z, a.w + b.w);
    }
}

extern "C" void kernel_launch(void* const* d_in, const int* in_sizes, int n_in,
                              void* d_out, int out_size, void* d_ws, size_t ws_size,
                              hipStream_t stream)
{
    const float* x1 = (const float*)d_in[0];
    const float* x2 = (const float*)d_in[1];
    const float* Wb = (const float*)d_in[2];
    const float* bb = (const float*)d_in[3];
    const float* Wc = (const float*)d_in[4];
    const float* bc = (const float*)d_in[5];
    const float* Wd = (const float*)d_in[6];
    const float* bd = (const float*)d_in[7];
    const float* alpha = (const float*)d_in[8];
    const float* beta  = (const float*)d_in[9];
    float* out = (float*)d_out;

    // ws layout (u16 units):
    u16* ws  = (u16*)d_ws;
    u16* x1T = ws;                      // [2][4096][512]  = 4,194,304
    u16* x2T = ws + 4194304;            //                 = 4,194,304
    u16* yab1 = ws + 8388608;           // [2][4096][128]  = 1,048,576
    u16* yab2 = ws + 9437184;           //                 = 1,048,576
    u16* ft   = ws + 10485760;          // [2][512][4096]  = 4,194,304
    u16* W1   = ws + 14680064;          // [640][512]      =   327,680
    u16* W2f  = ws + 15007744;          // [512][512]      =   262,144
    float* denom = (float*)(ws + 15269888);   // [2][2][4096] f32
    float* partial = (float*)ws;        // overlays x1T/x2T after GEMMs (16.8 MB)

    hipMemsetAsync(denom, 0, (size_t)2 * NB * NT * sizeof(float), stream);
    k_convW<<<1152, 256, 0, stream>>>(Wb, Wc, Wd, alpha, beta, W1, W2f);
    k_prep<<<dim3(8, 64, 4), 256, 0, stream>>>(x1, x2, x1T, x2T);
    k_gemm<1><<<dim3(32, 5, 2), 256, 0, stream>>>(W1, W2f, x1T, bb, bc, bd, alpha, beta, yab1, ft);
    k_gemm<2><<<dim3(32, 5, 2), 256, 0, stream>>>(W1, W2f, x2T, bb, bc, bd, alpha, beta, yab2, ft);
    k_denom<<<2048, 256, 0, stream>>>(yab1, yab2, denom);
    k_papply<<<512, 256, 0, stream>>>(yab1, yab2, ft, denom, out, partial);
    k_reduce<<<2048, 256, 0, stream>>>(out, partial, NB * CDIM * NT / 4);
}

// Round 7
// 428.717 us; speedup vs baseline: 1.2781x; 1.2781x over previous
//
#include <hip/hip_runtime.h>
#include <math.h>

#define NB 2
#define CDIM 512
#define NT 4096
#define LOG2E 1.44269504088896f
#define SHIFT 20.0f

typedef unsigned short u16;
typedef __attribute__((ext_vector_type(8))) short short8;
typedef __attribute__((ext_vector_type(4))) float f32x4;

union U8 { u16 v[8]; uint4 u4; };
union U4 { u16 v[4]; uint2 u2; };

__device__ __forceinline__ u16 f2bf(float f) {
    union { float f; unsigned u; } v; v.f = f;
    unsigned r = (v.u + 0x7fffu + ((v.u >> 16) & 1u)) >> 16;
    return (u16)r;
}
__device__ __forceinline__ float bf2f(u16 b) {
    union { float f; unsigned u; } v; v.u = ((unsigned)b) << 16; return v.f;
}
__device__ __forceinline__ float fexp2(float x) { return exp2f(x); }
__device__ __forceinline__ float flog2(float x) { return log2f(x); }

// ---------------- weight convert: W1=[Wb*log2e; Wc; alpha*Wd] bf16, W2f=beta*Wd bf16 ----------------
__global__ __launch_bounds__(256) void k_convW(
    const float* __restrict__ Wb, const float* __restrict__ Wc, const float* __restrict__ Wd,
    const float* __restrict__ alpha, const float* __restrict__ beta,
    u16* __restrict__ W1, u16* __restrict__ W2f)
{
    int r = blockIdx.x, t = threadIdx.x;
    const float* src; float scale; u16* dst;
    if (r < 640) {
        dst = W1 + (size_t)r * CDIM;
        if (r < 64)       { src = Wb + (size_t)r * CDIM;        scale = LOG2E; }
        else if (r < 128) { src = Wc + (size_t)(r - 64) * CDIM; scale = 1.f; }
        else              { src = Wd + (size_t)(r - 128) * CDIM; scale = alpha[0]; }
    } else {
        int rr = r - 640;
        dst = W2f + (size_t)rr * CDIM;
        src = Wd + (size_t)rr * CDIM;
        scale = beta[0];
    }
    float2 v = *(const float2*)&src[t * 2];
    unsigned p = (unsigned)f2bf(v.x * scale) | ((unsigned)f2bf(v.y * scale) << 16);
    *(unsigned*)&dst[t * 2] = p;
}

// ---------------- x [b][c][n] fp32 -> xT [b][n][c] bf16 (64x64 tiles via LDS) ----------------
__global__ __launch_bounds__(256) void k_prep(
    const float* __restrict__ x1, const float* __restrict__ x2,
    u16* __restrict__ x1T, u16* __restrict__ x2T)
{
    __shared__ float Lt[64][65];
    int t = threadIdx.x;
    int c0 = blockIdx.x * 64, n0 = blockIdx.y * 64;
    int which = blockIdx.z & 1, batch = blockIdx.z >> 1;
    const float* src = (which ? x2 : x1) + (size_t)batch * CDIM * NT;
    u16* dst = (which ? x2T : x1T) + (size_t)batch * NT * CDIM;
    #pragma unroll
    for (int p = 0; p < 4; p++) {
        int cr = p * 16 + (t >> 4), nc = (t & 15) * 4;
        float4 v = *(const float4*)&src[(size_t)(c0 + cr) * NT + n0 + nc];
        Lt[cr][nc] = v.x; Lt[cr][nc + 1] = v.y; Lt[cr][nc + 2] = v.z; Lt[cr][nc + 3] = v.w;
    }
    __syncthreads();
    #pragma unroll
    for (int p = 0; p < 2; p++) {
        int nr = p * 32 + (t >> 3), cc = (t & 7) * 8;
        U8 u;
        #pragma unroll
        for (int j = 0; j < 8; j++) u.v[j] = f2bf(Lt[cc + j][nr]);
        *(uint4*)&dst[(size_t)(n0 + nr) * CDIM + c0 + cc] = u.u4;
    }
}

// ---------------- projection GEMM (bf16 MFMA, K=512) ----------------
template<int WHICH>
__global__ __launch_bounds__(256, 2) void k_gemm(
    const u16* __restrict__ W1, const u16* __restrict__ W2f,
    const u16* __restrict__ xT,
    const float* __restrict__ bb, const float* __restrict__ bc, const float* __restrict__ bd,
    const float* __restrict__ alpha, const float* __restrict__ beta,
    u16* __restrict__ yab, u16* __restrict__ ft)
{
    __shared__ u16 Wt[128][72];
    __shared__ u16 Xt[128][72];
    int t = threadIdx.x, lane = t & 63, w = t >> 6, q = lane >> 4, l15 = lane & 15;
    int nT_ = blockIdx.x, oT = blockIdx.y, batch = blockIdx.z;
    int n0 = nT_ * 128, o0 = oT * 128;
    const u16* Wsrc = (WHICH == 1 || oT == 0) ? (W1 + (size_t)o0 * CDIM)
                                              : (W2f + (size_t)(o0 - 128) * CDIM);
    const u16* xb = xT + ((size_t)batch * NT + n0) * CDIM;
    f32x4 acc[2][8];
    #pragma unroll
    for (int a = 0; a < 2; a++)
        #pragma unroll
        for (int b = 0; b < 8; b++) { f32x4 z = {0.f,0.f,0.f,0.f}; acc[a][b] = z; }

    for (int k0 = 0; k0 < CDIM; k0 += 64) {
        if (k0) __syncthreads();
        int r = t >> 1, h = t & 1;
        #pragma unroll
        for (int u = 0; u < 4; u++) {
            *(uint4*)&Wt[r][h * 32 + u * 8] = *(const uint4*)&Wsrc[(size_t)r * CDIM + k0 + h * 32 + u * 8];
            *(uint4*)&Xt[r][h * 32 + u * 8] = *(const uint4*)&xb[(size_t)r * CDIM + k0 + h * 32 + u * 8];
        }
        __syncthreads();
        if (oT == 0) {
            short8 af[2][2];
            #pragma unroll
            for (int ot = 0; ot < 2; ot++)
                #pragma unroll
                for (int kk = 0; kk < 2; kk++)
                    af[ot][kk] = *(const short8*)&Wt[w * 32 + ot * 16 + l15][kk * 32 + q * 8];
            #pragma unroll
            for (int kk = 0; kk < 2; kk++)
                #pragma unroll
                for (int i = 0; i < 8; i++) {
                    short8 bf = *(const short8*)&Xt[i * 16 + l15][kk * 32 + q * 8];
                    #pragma unroll
                    for (int ot = 0; ot < 2; ot++)
                        acc[ot][i] = __builtin_amdgcn_mfma_f32_16x16x32_bf16(af[ot][kk], bf, acc[ot][i], 0, 0, 0);
                }
        } else {
            short8 wf[2][2];
            #pragma unroll
            for (int ct = 0; ct < 2; ct++)
                #pragma unroll
                for (int kk = 0; kk < 2; kk++)
                    wf[ct][kk] = *(const short8*)&Wt[w * 32 + ct * 16 + l15][kk * 32 + q * 8];
            #pragma unroll
            for (int kk = 0; kk < 2; kk++)
                #pragma unroll
                for (int i = 0; i < 8; i++) {
                    short8 xf = *(const short8*)&Xt[i * 16 + l15][kk * 32 + q * 8];
                    #pragma unroll
                    for (int ct = 0; ct < 2; ct++)
                        acc[ct][i] = __builtin_amdgcn_mfma_f32_16x16x32_bf16(xf, wf[ct][kk], acc[ct][i], 0, 0, 0);
                }
        }
    }

    if (oT == 0) {
        #pragma unroll
        for (int ot = 0; ot < 2; ot++)
            #pragma unroll
            for (int i = 0; i < 8; i++) {
                int obase = w * 32 + ot * 16 + q * 4;
                int n = n0 + i * 16 + l15;
                U4 u;
                #pragma unroll
                for (int r = 0; r < 4; r++) {
                    int o = obase + r;
                    float bias = (o < 64) ? bb[o] * LOG2E : bc[o - 64];
                    u.v[r] = f2bf(acc[ot][i][r] + bias);
                }
                *(uint2*)&yab[((size_t)batch * NT + n) * 128 + obase] = u.u2;
            }
    } else {
        float bscale = (WHICH == 2) ? (alpha[0] + beta[0]) : 0.f;
        #pragma unroll
        for (int ct = 0; ct < 2; ct++)
            #pragma unroll
            for (int i = 0; i < 8; i++) {
                int c = (o0 - 128) + w * 32 + ct * 16 + l15;
                int mb = n0 + i * 16 + q * 4;
                u16* dst = &ft[((size_t)batch * CDIM + c) * NT + mb];
                U4 u;
                if (WHICH == 1) {
                    #pragma unroll
                    for (int r = 0; r < 4; r++) u.v[r] = f2bf(acc[ct][i][r]);
                } else {
                    U4 old; old.u2 = *(const uint2*)dst;
                    float bias = bd[c] * bscale;
                    #pragma unroll
                    for (int r = 0; r < 4; r++) u.v[r] = f2bf(acc[ct][i][r] + bf2f(old.v[r]) + bias);
                }
                *(uint2*)dst = u.u2;
            }
    }
}

// ---------------- denominators: denom[dir][b][n] = sum_m exp2(S - SHIFT) ----------------
__global__ __launch_bounds__(256, 4) void k_denom(
    const u16* __restrict__ yab1, const u16* __restrict__ yab2,
    float* __restrict__ denom)
{
    int t = threadIdx.x, lane = t & 63, w = t >> 6, q = lane >> 4, l15 = lane & 15;
    int x = blockIdx.x & 15;
    int batch = x & 1, m8 = x >> 1;
    int n0 = (blockIdx.x >> 4) * 32;
    const u16* y1 = yab1 + (size_t)batch * NT * 128;
    const u16* y2 = yab2 + (size_t)batch * NT * 128;

    short8 a1f[2][2], a2f[2][2];
    #pragma unroll
    for (int i = 0; i < 2; i++)
        #pragma unroll
        for (int kk = 0; kk < 2; kk++) {
            a1f[i][kk] = *(const short8*)&y1[(size_t)(n0 + i * 16 + l15) * 128 + kk * 32 + q * 8];
            a2f[i][kk] = *(const short8*)&y2[(size_t)(n0 + i * 16 + l15) * 128 + kk * 32 + q * 8];
        }

    float sm[2][2] = {{0.f,0.f},{0.f,0.f}};
    for (int mc = 0; mc < 512; mc += 64) {
        int mrow = m8 * 512 + mc + w * 16 + l15;
        const u16* r1 = y1 + (size_t)mrow * 128 + 64;
        const u16* r2 = y2 + (size_t)mrow * 128 + 64;
        short8 b1k0 = *(const short8*)(r1 + q * 8);
        short8 b1k1 = *(const short8*)(r1 + 32 + q * 8);
        short8 b2k0 = *(const short8*)(r2 + q * 8);
        short8 b2k1 = *(const short8*)(r2 + 32 + q * 8);
        #pragma unroll
        for (int i = 0; i < 2; i++) {
            f32x4 z = {0.f,0.f,0.f,0.f};
            f32x4 s12 = __builtin_amdgcn_mfma_f32_16x16x32_bf16(b2k0, a1f[i][0], z, 0, 0, 0);
            s12 = __builtin_amdgcn_mfma_f32_16x16x32_bf16(b2k1, a1f[i][1], s12, 0, 0, 0);
            f32x4 s21 = __builtin_amdgcn_mfma_f32_16x16x32_bf16(b1k0, a2f[i][0], z, 0, 0, 0);
            s21 = __builtin_amdgcn_mfma_f32_16x16x32_bf16(b1k1, a2f[i][1], s21, 0, 0, 0);
            #pragma unroll
            for (int r = 0; r < 4; r++) {
                sm[0][i] += fexp2(s12[r] - SHIFT);
                sm[1][i] += fexp2(s21[r] - SHIFT);
            }
        }
    }
    #pragma unroll
    for (int d = 0; d < 2; d++)
        #pragma unroll
        for (int i = 0; i < 2; i++) {
            float v = sm[d][i];
            v += __shfl_xor(v, 16);
            v += __shfl_xor(v, 32);
            if (q == 0)
                atomicAdd(&denom[((size_t)d * NB + batch) * NT + n0 + i * 16 + l15], v);
        }
}

// ---------------- P materialize: P[n][m] = |p12 - p21| bf16 (one batch) ----------------
// k_denom skeleton: no LDS, no barriers; D rows = 4 consecutive m -> 8B stores, 32B/row per wave.
__global__ __launch_bounds__(256, 4) void k_pmat(
    const u16* __restrict__ y1, const u16* __restrict__ y2,
    const float* __restrict__ d12, const float* __restrict__ d21,
    u16* __restrict__ P)
{
    int t = threadIdx.x, lane = t & 63, w = t >> 6, q = lane >> 4, l15 = lane & 15;
    int m8 = blockIdx.x & 7;
    int n0 = (blockIdx.x >> 3) * 32;

    short8 a1f[2][2], a2f[2][2];
    #pragma unroll
    for (int i = 0; i < 2; i++)
        #pragma unroll
        for (int kk = 0; kk < 2; kk++) {
            a1f[i][kk] = *(const short8*)&y1[(size_t)(n0 + i * 16 + l15) * 128 + kk * 32 + q * 8];
            a2f[i][kk] = *(const short8*)&y2[(size_t)(n0 + i * 16 + l15) * 128 + kk * 32 + q * 8];
        }
    float ls12[2], ls21[2];
    #pragma unroll
    for (int i = 0; i < 2; i++) {
        ls12[i] = SHIFT + flog2(d12[n0 + i * 16 + l15]);
        ls21[i] = SHIFT + flog2(d21[n0 + i * 16 + l15]);
    }

    for (int mc = 0; mc < 512; mc += 64) {
        int mrow = m8 * 512 + mc + w * 16;
        const u16* r1 = y1 + (size_t)(mrow + l15) * 128 + 64;
        const u16* r2 = y2 + (size_t)(mrow + l15) * 128 + 64;
        short8 b1k0 = *(const short8*)(r1 + q * 8);
        short8 b1k1 = *(const short8*)(r1 + 32 + q * 8);
        short8 b2k0 = *(const short8*)(r2 + q * 8);
        short8 b2k1 = *(const short8*)(r2 + 32 + q * 8);
        #pragma unroll
        for (int i = 0; i < 2; i++) {
            f32x4 z = {0.f,0.f,0.f,0.f};
            f32x4 s12 = __builtin_amdgcn_mfma_f32_16x16x32_bf16(b2k0, a1f[i][0], z, 0, 0, 0);
            s12 = __builtin_amdgcn_mfma_f32_16x16x32_bf16(b2k1, a1f[i][1], s12, 0, 0, 0);
            f32x4 s21 = __builtin_amdgcn_mfma_f32_16x16x32_bf16(b1k0, a2f[i][0], z, 0, 0, 0);
            s21 = __builtin_amdgcn_mfma_f32_16x16x32_bf16(b1k1, a2f[i][1], s21, 0, 0, 0);
            U4 u;
            #pragma unroll
            for (int r = 0; r < 4; r++)
                u.v[r] = f2bf(fabsf(fexp2(s12[r] - ls12[i]) - fexp2(s21[r] - ls21[i])));
            *(uint2*)&P[(size_t)(n0 + i * 16 + l15) * NT + mrow + q * 4] = u.u2;
        }
    }
}

// ---------------- apply: out[c][n] = sum_m ft[c][m] * P[n][m]  (clean GEMM, one batch) ----------------
// block = 128c x 64n, BK=128, m-split 2.  P staged in padded LDS (2-way-free banks);
// ft A-frags direct from global (per-XCD 512KB slice is L2-resident: xcd bits = (ms,cb)).
__global__ __launch_bounds__(256, 2) void k_apply(
    const u16* __restrict__ P, const u16* __restrict__ ftb,
    float* __restrict__ out_b, float* __restrict__ part_b)
{
    __shared__ u16 Pt[64][136];
    int t = threadIdx.x, lane = t & 63, w = t >> 6, q = lane >> 4, l15 = lane & 15;
    int blk = blockIdx.x;
    int ms = blk & 1, cb = (blk >> 1) & 3, nb = blk >> 3;
    int c0 = cb * 128, n0 = nb * 64, m0 = ms * 2048;
    int wc = w >> 1, wq = w & 1;                  // wave tile: 64c x 32n
    const u16* ftg = ftb + (size_t)(c0 + wc * 64) * NT;

    f32x4 acc[4][2];
    #pragma unroll
    for (int ct = 0; ct < 4; ct++)
        #pragma unroll
        for (int nt = 0; nt < 2; nt++) { f32x4 z = {0.f,0.f,0.f,0.f}; acc[ct][nt] = z; }

    int srow = t >> 2, soff = (t & 3) * 32;
    for (int mc = 0; mc < 2048; mc += 128) {
        int mm = m0 + mc;
        // stage P tile 64n x 128m (manual, padded rows)
        uint4 sv[4];
        #pragma unroll
        for (int u = 0; u < 4; u++)
            sv[u] = *(const uint4*)&P[(size_t)(n0 + srow) * NT + mm + soff + u * 8];
        __syncthreads();
        #pragma unroll
        for (int u = 0; u < 4; u++)
            *(uint4*)&Pt[srow][soff + u * 8] = sv[u];
        __syncthreads();

        // A-frags (ft) direct from global, all issued before MFMAs
        short8 af[4][4];   // [k][ct]
        #pragma unroll
        for (int k = 0; k < 4; k++)
            #pragma unroll
            for (int ct = 0; ct < 4; ct++)
                af[k][ct] = *(const short8*)&ftg[(size_t)(ct * 16 + l15) * NT + mm + k * 32 + q * 8];
        short8 bf[4][2];
        #pragma unroll
        for (int k = 0; k < 4; k++) {
            bf[k][0] = *(const short8*)&Pt[wq * 32 + l15][k * 32 + q * 8];
            bf[k][1] = *(const short8*)&Pt[wq * 32 + 16 + l15][k * 32 + q * 8];
        }
        #pragma unroll
        for (int k = 0; k < 4; k++)
            #pragma unroll
            for (int ct = 0; ct < 4; ct++) {
                acc[ct][0] = __builtin_amdgcn_mfma_f32_16x16x32_bf16(af[k][ct], bf[k][0], acc[ct][0], 0, 0, 0);
                acc[ct][1] = __builtin_amdgcn_mfma_f32_16x16x32_bf16(af[k][ct], bf[k][1], acc[ct][1], 0, 0, 0);
            }
    }

    float* dst = ms ? part_b : out_b;
    #pragma unroll
    for (int ct = 0; ct < 4; ct++)
        #pragma unroll
        for (int nt = 0; nt < 2; nt++) {
            int c = c0 + wc * 64 + ct * 16 + q * 4;
            int n = n0 + wq * 32 + nt * 16 + l15;
            #pragma unroll
            for (int r = 0; r < 4; r++)
                dst[(size_t)(c + r) * NT + n] = acc[ct][nt][r];
        }
}

// ---------------- out += partial ----------------
__global__ __launch_bounds__(256) void k_reduce(
    float* __restrict__ out, const float* __restrict__ part, int n4)
{
    int i = blockIdx.x * 256 + threadIdx.x, stride = gridDim.x * 256;
    float4* o4 = (float4*)out;
    const float4* p4 = (const float4*)part;
    for (int j = i; j < n4; j += stride) {
        float4 a = o4[j], b = p4[j];
        o4[j] = make_float4(a.x + b.x, a.y + b.y, a.z + b.z, a.w + b.w);
    }
}

extern "C" void kernel_launch(void* const* d_in, const int* in_sizes, int n_in,
                              void* d_out, int out_size, void* d_ws, size_t ws_size,
                              hipStream_t stream)
{
    const float* x1 = (const float*)d_in[0];
    const float* x2 = (const float*)d_in[1];
    const float* Wb = (const float*)d_in[2];
    const float* bb = (const float*)d_in[3];
    const float* Wc = (const float*)d_in[4];
    const float* bc = (const float*)d_in[5];
    const float* Wd = (const float*)d_in[6];
    const float* bd = (const float*)d_in[7];
    const float* alpha = (const float*)d_in[8];
    const float* beta  = (const float*)d_in[9];
    float* out = (float*)d_out;

    // ws layout (u16 units), total ~64.2 MB:
    u16* ws  = (u16*)d_ws;
    u16* yab1 = ws;                             // [2][4096][128]  1,048,576
    u16* yab2 = ws + 1048576;                   //                 1,048,576
    u16* ft   = ws + 2097152;                   // [2][512][4096]  4,194,304
    u16* W1   = ws + 6291456;                   // [640][512]        327,680
    u16* W2f  = ws + 6619136;                   // [512][512]        262,144
    float* denom = (float*)(ws + 6881280);      // [2][2][4096] f32   32,768
    u16* P    = ws + 6914048;                   // [4096][4096]   16,777,216 (one batch)
    u16* x1T  = P;                              // overlay: dead before P written
    u16* x2T  = P + 4194304;
    float* partial = (float*)(ws + 23691264);   // [2][512][4096] f32  8,388,608

    hipMemsetAsync(denom, 0, (size_t)2 * NB * NT * sizeof(float), stream);
    k_convW<<<1152, 256, 0, stream>>>(Wb, Wc, Wd, alpha, beta, W1, W2f);
    k_prep<<<dim3(8, 64, 4), 256, 0, stream>>>(x1, x2, x1T, x2T);
    k_gemm<1><<<dim3(32, 5, 2), 256, 0, stream>>>(W1, W2f, x1T, bb, bc, bd, alpha, beta, yab1, ft);
    k_gemm<2><<<dim3(32, 5, 2), 256, 0, stream>>>(W1, W2f, x2T, bb, bc, bd, alpha, beta, yab2, ft);
    k_denom<<<2048, 256, 0, stream>>>(yab1, yab2, denom);
    for (int b = 0; b < NB; b++) {
        k_pmat<<<1024, 256, 0, stream>>>(
            yab1 + (size_t)b * NT * 128, yab2 + (size_t)b * NT * 128,
            denom + (size_t)b * NT, denom + (size_t)(NB + b) * NT, P);
        k_apply<<<512, 256, 0, stream>>>(
            P, ft + (size_t)b * CDIM * NT,
            out + (size_t)b * CDIM * NT, partial + (size_t)b * CDIM * NT);
    }
    k_reduce<<<2048, 256, 0, stream>>>(out, partial, NB * CDIM * NT / 4);
}

// Round 8
// 335.983 us; speedup vs baseline: 1.6309x; 1.2760x over previous
//
#include <hip/hip_runtime.h>
#include <math.h>

#define NB 2
#define CDIM 512
#define NT 4096
#define LOG2E 1.44269504088896f
#define SHIFT 20.0f

typedef unsigned short u16;
typedef __attribute__((ext_vector_type(8))) short short8;
typedef __attribute__((ext_vector_type(4))) float f32x4;

union U8 { u16 v[8]; uint4 u4; };
union U4 { u16 v[4]; uint2 u2; };

__device__ __forceinline__ u16 f2bf(float f) {
    union { float f; unsigned u; } v; v.f = f;
    unsigned r = (v.u + 0x7fffu + ((v.u >> 16) & 1u)) >> 16;
    return (u16)r;
}
__device__ __forceinline__ float bf2f(u16 b) {
    union { float f; unsigned u; } v; v.u = ((unsigned)b) << 16; return v.f;
}
__device__ __forceinline__ float fexp2(float x) { return exp2f(x); }
__device__ __forceinline__ float flog2(float x) { return log2f(x); }

// async global->LDS, 16B per lane, dest = uniform base + lane*16
#define GLDS(g, l) __builtin_amdgcn_global_load_lds( \
    (const __attribute__((address_space(1))) unsigned int*)(g), \
    (__attribute__((address_space(3))) unsigned int*)(l), 16, 0, 0)

// ---------------- weight convert: W1=[Wb*log2e; Wc; alpha*Wd] bf16, W2f=beta*Wd bf16 ----------------
__global__ __launch_bounds__(256) void k_convW(
    const float* __restrict__ Wb, const float* __restrict__ Wc, const float* __restrict__ Wd,
    const float* __restrict__ alpha, const float* __restrict__ beta,
    u16* __restrict__ W1, u16* __restrict__ W2f)
{
    int r = blockIdx.x, t = threadIdx.x;
    const float* src; float scale; u16* dst;
    if (r < 640) {
        dst = W1 + (size_t)r * CDIM;
        if (r < 64)       { src = Wb + (size_t)r * CDIM;        scale = LOG2E; }
        else if (r < 128) { src = Wc + (size_t)(r - 64) * CDIM; scale = 1.f; }
        else              { src = Wd + (size_t)(r - 128) * CDIM; scale = alpha[0]; }
    } else {
        int rr = r - 640;
        dst = W2f + (size_t)rr * CDIM;
        src = Wd + (size_t)rr * CDIM;
        scale = beta[0];
    }
    float2 v = *(const float2*)&src[t * 2];
    unsigned p = (unsigned)f2bf(v.x * scale) | ((unsigned)f2bf(v.y * scale) << 16);
    *(unsigned*)&dst[t * 2] = p;
}

// ---------------- x [b][c][n] fp32 -> xT [b][n][c] bf16 (64x64 tiles via LDS) ----------------
__global__ __launch_bounds__(256) void k_prep(
    const float* __restrict__ x1, const float* __restrict__ x2,
    u16* __restrict__ x1T, u16* __restrict__ x2T)
{
    __shared__ float Lt[64][65];
    int t = threadIdx.x;
    int c0 = blockIdx.x * 64, n0 = blockIdx.y * 64;
    int which = blockIdx.z & 1, batch = blockIdx.z >> 1;
    const float* src = (which ? x2 : x1) + (size_t)batch * CDIM * NT;
    u16* dst = (which ? x2T : x1T) + (size_t)batch * NT * CDIM;
    #pragma unroll
    for (int p = 0; p < 4; p++) {
        int cr = p * 16 + (t >> 4), nc = (t & 15) * 4;
        float4 v = *(const float4*)&src[(size_t)(c0 + cr) * NT + n0 + nc];
        Lt[cr][nc] = v.x; Lt[cr][nc + 1] = v.y; Lt[cr][nc + 2] = v.z; Lt[cr][nc + 3] = v.w;
    }
    __syncthreads();
    #pragma unroll
    for (int p = 0; p < 2; p++) {
        int nr = p * 32 + (t >> 3), cc = (t & 7) * 8;
        U8 u;
        #pragma unroll
        for (int j = 0; j < 8; j++) u.v[j] = f2bf(Lt[cc + j][nr]);
        *(uint4*)&dst[(size_t)(n0 + nr) * CDIM + c0 + cc] = u.u4;
    }
}

// ---------------- projection GEMM (bf16 MFMA, K=512) ----------------
template<int WHICH>
__global__ __launch_bounds__(256, 2) void k_gemm(
    const u16* __restrict__ W1, const u16* __restrict__ W2f,
    const u16* __restrict__ xT,
    const float* __restrict__ bb, const float* __restrict__ bc, const float* __restrict__ bd,
    const float* __restrict__ alpha, const float* __restrict__ beta,
    u16* __restrict__ yab, u16* __restrict__ ft)
{
    __shared__ u16 Wt[128][72];
    __shared__ u16 Xt[128][72];
    int t = threadIdx.x, lane = t & 63, w = t >> 6, q = lane >> 4, l15 = lane & 15;
    int nT_ = blockIdx.x, oT = blockIdx.y, batch = blockIdx.z;
    int n0 = nT_ * 128, o0 = oT * 128;
    const u16* Wsrc = (WHICH == 1 || oT == 0) ? (W1 + (size_t)o0 * CDIM)
                                              : (W2f + (size_t)(o0 - 128) * CDIM);
    const u16* xb = xT + ((size_t)batch * NT + n0) * CDIM;
    f32x4 acc[2][8];
    #pragma unroll
    for (int a = 0; a < 2; a++)
        #pragma unroll
        for (int b = 0; b < 8; b++) { f32x4 z = {0.f,0.f,0.f,0.f}; acc[a][b] = z; }

    for (int k0 = 0; k0 < CDIM; k0 += 64) {
        if (k0) __syncthreads();
        int r = t >> 1, h = t & 1;
        #pragma unroll
        for (int u = 0; u < 4; u++) {
            *(uint4*)&Wt[r][h * 32 + u * 8] = *(const uint4*)&Wsrc[(size_t)r * CDIM + k0 + h * 32 + u * 8];
            *(uint4*)&Xt[r][h * 32 + u * 8] = *(const uint4*)&xb[(size_t)r * CDIM + k0 + h * 32 + u * 8];
        }
        __syncthreads();
        if (oT == 0) {
            short8 af[2][2];
            #pragma unroll
            for (int ot = 0; ot < 2; ot++)
                #pragma unroll
                for (int kk = 0; kk < 2; kk++)
                    af[ot][kk] = *(const short8*)&Wt[w * 32 + ot * 16 + l15][kk * 32 + q * 8];
            #pragma unroll
            for (int kk = 0; kk < 2; kk++)
                #pragma unroll
                for (int i = 0; i < 8; i++) {
                    short8 bf = *(const short8*)&Xt[i * 16 + l15][kk * 32 + q * 8];
                    #pragma unroll
                    for (int ot = 0; ot < 2; ot++)
                        acc[ot][i] = __builtin_amdgcn_mfma_f32_16x16x32_bf16(af[ot][kk], bf, acc[ot][i], 0, 0, 0);
                }
        } else {
            short8 wf[2][2];
            #pragma unroll
            for (int ct = 0; ct < 2; ct++)
                #pragma unroll
                for (int kk = 0; kk < 2; kk++)
                    wf[ct][kk] = *(const short8*)&Wt[w * 32 + ct * 16 + l15][kk * 32 + q * 8];
            #pragma unroll
            for (int kk = 0; kk < 2; kk++)
                #pragma unroll
                for (int i = 0; i < 8; i++) {
                    short8 xf = *(const short8*)&Xt[i * 16 + l15][kk * 32 + q * 8];
                    #pragma unroll
                    for (int ct = 0; ct < 2; ct++)
                        acc[ct][i] = __builtin_amdgcn_mfma_f32_16x16x32_bf16(xf, wf[ct][kk], acc[ct][i], 0, 0, 0);
                }
        }
    }

    if (oT == 0) {
        #pragma unroll
        for (int ot = 0; ot < 2; ot++)
            #pragma unroll
            for (int i = 0; i < 8; i++) {
                int obase = w * 32 + ot * 16 + q * 4;
                int n = n0 + i * 16 + l15;
                U4 u;
                #pragma unroll
                for (int r = 0; r < 4; r++) {
                    int o = obase + r;
                    float bias = (o < 64) ? bb[o] * LOG2E : bc[o - 64];
                    u.v[r] = f2bf(acc[ot][i][r] + bias);
                }
                *(uint2*)&yab[((size_t)batch * NT + n) * 128 + obase] = u.u2;
            }
    } else {
        float bscale = (WHICH == 2) ? (alpha[0] + beta[0]) : 0.f;
        #pragma unroll
        for (int ct = 0; ct < 2; ct++)
            #pragma unroll
            for (int i = 0; i < 8; i++) {
                int c = (o0 - 128) + w * 32 + ct * 16 + l15;
                int mb = n0 + i * 16 + q * 4;
                u16* dst = &ft[((size_t)batch * CDIM + c) * NT + mb];
                U4 u;
                if (WHICH == 1) {
                    #pragma unroll
                    for (int r = 0; r < 4; r++) u.v[r] = f2bf(acc[ct][i][r]);
                } else {
                    U4 old; old.u2 = *(const uint2*)dst;
                    float bias = bd[c] * bscale;
                    #pragma unroll
                    for (int r = 0; r < 4; r++) u.v[r] = f2bf(acc[ct][i][r] + bf2f(old.v[r]) + bias);
                }
                *(uint2*)dst = u.u2;
            }
    }
}

// ---------------- denominators: denom[dir][b][n] = sum_m exp2(S - SHIFT) ----------------
__global__ __launch_bounds__(256, 4) void k_denom(
    const u16* __restrict__ yab1, const u16* __restrict__ yab2,
    float* __restrict__ denom)
{
    int t = threadIdx.x, lane = t & 63, w = t >> 6, q = lane >> 4, l15 = lane & 15;
    int x = blockIdx.x & 15;
    int batch = x & 1, m8 = x >> 1;
    int n0 = (blockIdx.x >> 4) * 32;
    const u16* y1 = yab1 + (size_t)batch * NT * 128;
    const u16* y2 = yab2 + (size_t)batch * NT * 128;

    short8 a1f[2][2], a2f[2][2];
    #pragma unroll
    for (int i = 0; i < 2; i++)
        #pragma unroll
        for (int kk = 0; kk < 2; kk++) {
            a1f[i][kk] = *(const short8*)&y1[(size_t)(n0 + i * 16 + l15) * 128 + kk * 32 + q * 8];
            a2f[i][kk] = *(const short8*)&y2[(size_t)(n0 + i * 16 + l15) * 128 + kk * 32 + q * 8];
        }

    float sm[2][2] = {{0.f,0.f},{0.f,0.f}};
    for (int mc = 0; mc < 512; mc += 64) {
        int mrow = m8 * 512 + mc + w * 16 + l15;
        const u16* r1 = y1 + (size_t)mrow * 128 + 64;
        const u16* r2 = y2 + (size_t)mrow * 128 + 64;
        short8 b1k0 = *(const short8*)(r1 + q * 8);
        short8 b1k1 = *(const short8*)(r1 + 32 + q * 8);
        short8 b2k0 = *(const short8*)(r2 + q * 8);
        short8 b2k1 = *(const short8*)(r2 + 32 + q * 8);
        #pragma unroll
        for (int i = 0; i < 2; i++) {
            f32x4 z = {0.f,0.f,0.f,0.f};
            f32x4 s12 = __builtin_amdgcn_mfma_f32_16x16x32_bf16(b2k0, a1f[i][0], z, 0, 0, 0);
            s12 = __builtin_amdgcn_mfma_f32_16x16x32_bf16(b2k1, a1f[i][1], s12, 0, 0, 0);
            f32x4 s21 = __builtin_amdgcn_mfma_f32_16x16x32_bf16(b1k0, a2f[i][0], z, 0, 0, 0);
            s21 = __builtin_amdgcn_mfma_f32_16x16x32_bf16(b1k1, a2f[i][1], s21, 0, 0, 0);
            #pragma unroll
            for (int r = 0; r < 4; r++) {
                sm[0][i] += fexp2(s12[r] - SHIFT);
                sm[1][i] += fexp2(s21[r] - SHIFT);
            }
        }
    }
    #pragma unroll
    for (int d = 0; d < 2; d++)
        #pragma unroll
        for (int i = 0; i < 2; i++) {
            float v = sm[d][i];
            v += __shfl_xor(v, 16);
            v += __shfl_xor(v, 32);
            if (q == 0)
                atomicAdd(&denom[((size_t)d * NB + batch) * NT + n0 + i * 16 + l15], v);
        }
}

// ---------------- P materialize: P[n][m] = |p12 - p21| bf16 (one batch) ----------------
__global__ __launch_bounds__(256, 4) void k_pmat(
    const u16* __restrict__ y1, const u16* __restrict__ y2,
    const float* __restrict__ d12, const float* __restrict__ d21,
    u16* __restrict__ P)
{
    int t = threadIdx.x, lane = t & 63, w = t >> 6, q = lane >> 4, l15 = lane & 15;
    int m8 = blockIdx.x & 7;
    int n0 = (blockIdx.x >> 3) * 32;

    short8 a1f[2][2], a2f[2][2];
    #pragma unroll
    for (int i = 0; i < 2; i++)
        #pragma unroll
        for (int kk = 0; kk < 2; kk++) {
            a1f[i][kk] = *(const short8*)&y1[(size_t)(n0 + i * 16 + l15) * 128 + kk * 32 + q * 8];
            a2f[i][kk] = *(const short8*)&y2[(size_t)(n0 + i * 16 + l15) * 128 + kk * 32 + q * 8];
        }
    float ls12[2], ls21[2];
    #pragma unroll
    for (int i = 0; i < 2; i++) {
        ls12[i] = SHIFT + flog2(d12[n0 + i * 16 + l15]);
        ls21[i] = SHIFT + flog2(d21[n0 + i * 16 + l15]);
    }

    for (int mc = 0; mc < 512; mc += 64) {
        int mrow = m8 * 512 + mc + w * 16;
        const u16* r1 = y1 + (size_t)(mrow + l15) * 128 + 64;
        const u16* r2 = y2 + (size_t)(mrow + l15) * 128 + 64;
        short8 b1k0 = *(const short8*)(r1 + q * 8);
        short8 b1k1 = *(const short8*)(r1 + 32 + q * 8);
        short8 b2k0 = *(const short8*)(r2 + q * 8);
        short8 b2k1 = *(const short8*)(r2 + 32 + q * 8);
        #pragma unroll
        for (int i = 0; i < 2; i++) {
            f32x4 z = {0.f,0.f,0.f,0.f};
            f32x4 s12 = __builtin_amdgcn_mfma_f32_16x16x32_bf16(b2k0, a1f[i][0], z, 0, 0, 0);
            s12 = __builtin_amdgcn_mfma_f32_16x16x32_bf16(b2k1, a1f[i][1], s12, 0, 0, 0);
            f32x4 s21 = __builtin_amdgcn_mfma_f32_16x16x32_bf16(b1k0, a2f[i][0], z, 0, 0, 0);
            s21 = __builtin_amdgcn_mfma_f32_16x16x32_bf16(b1k1, a2f[i][1], s21, 0, 0, 0);
            U4 u;
            #pragma unroll
            for (int r = 0; r < 4; r++)
                u.v[r] = f2bf(fabsf(fexp2(s12[r] - ls12[i]) - fexp2(s21[r] - ls21[i])));
            *(uint2*)&P[(size_t)(n0 + i * 16 + l15) * NT + mrow + q * 4] = u.u2;
        }
    }
}

// ---------------- apply: out[c][n] = sum_m ft[c][m] * P[n][m]  (m97-style GEMM, one batch) ----------------
// 64c x 128n x BK64 tiles, m-split 2; global_load_lds(16B) double-buffered staging (1 barrier/iter);
// XOR-swizzled 16B units (no padding - required by global_load_lds) for conflict-min ds_read_b128;
// LDS-transpose epilogue -> full-line 512B row stores.  bid&7 = cb -> per-XCD ft slice L2-resident.
__global__ __launch_bounds__(256, 2) void k_apply(
    const u16* __restrict__ P, const u16* __restrict__ ftb,
    float* __restrict__ out_b, float* __restrict__ part_b)
{
    __shared__ __align__(16) union SMem {
        u16 stage[2][12288];       // per buf: A [64][64] @0, B [128][64] @4096
        float ep[64 * 132];        // epilogue transpose
    } sm;
    int t = threadIdx.x, lane = t & 63, w = t >> 6, q = lane >> 4, l15 = lane & 15;
    int bid = blockIdx.x;
    int cb = bid & 7, nb = (bid >> 3) & 31, ms = bid >> 8;
    int c0 = cb * 64, n0 = nb * 128, m0 = ms * 2048;
    const u16* ftg = ftb + (size_t)c0 * NT + m0;
    const u16* Pg  = P + (size_t)n0 * NT + m0;
    int rlo = lane >> 3, su = lane & 7;

    f32x4 acc[4][2];
    #pragma unroll
    for (int ct = 0; ct < 4; ct++)
        #pragma unroll
        for (int nt = 0; nt < 2; nt++) { f32x4 z = {0.f,0.f,0.f,0.f}; acc[ct][nt] = z; }

    // ---- stage one BK=64 tile into buf (async, 6 wave-issues: 2 A + 4 B) ----
    auto stage = [&](u16* buf, int moff) {
        #pragma unroll
        for (int ti = 0; ti < 2; ti++) {
            int row = w * 16 + ti * 8 + rlo;
            const u16* g = ftg + (size_t)row * NT + moff + ((su ^ (row & 7)) << 3);
            GLDS(g, buf + (w * 16 + ti * 8) * 64);
        }
        u16* Bs = buf + 4096;
        #pragma unroll
        for (int ti = 0; ti < 4; ti++) {
            int row = w * 32 + ti * 8 + rlo;
            const u16* g = Pg + (size_t)row * NT + moff + ((su ^ (row & 7)) << 3);
            GLDS(g, Bs + (w * 32 + ti * 8) * 64);
        }
    };

    stage(sm.stage[0], 0);
    int pb = 0;
    for (int it = 0; it < 32; it++) {
        __syncthreads();                                  // drains vmcnt -> buf[pb] ready
        if (it + 1 < 32)
            stage(sm.stage[pb ^ 1], (it + 1) * 64);       // full compute phase of slack
        const u16* As = sm.stage[pb];
        const u16* Bs = As + 4096;
        short8 af[2][4], bf[2][2];
        #pragma unroll
        for (int k = 0; k < 2; k++) {
            int sw = ((k * 4 + q) ^ (l15 & 7)) << 3;
            #pragma unroll
            for (int ct = 0; ct < 4; ct++)
                af[k][ct] = *(const short8*)&As[(ct * 16 + l15) * 64 + sw];
            #pragma unroll
            for (int nt = 0; nt < 2; nt++)
                bf[k][nt] = *(const short8*)&Bs[(w * 32 + nt * 16 + l15) * 64 + sw];
        }
        #pragma unroll
        for (int k = 0; k < 2; k++)
            #pragma unroll
            for (int ct = 0; ct < 4; ct++)
                #pragma unroll
                for (int nt = 0; nt < 2; nt++)
                    acc[ct][nt] = __builtin_amdgcn_mfma_f32_16x16x32_bf16(af[k][ct], bf[k][nt], acc[ct][nt], 0, 0, 0);
        pb ^= 1;
    }

    // ---- epilogue: LDS transpose -> full-line coalesced stores ----
    __syncthreads();
    #pragma unroll
    for (int ct = 0; ct < 4; ct++)
        #pragma unroll
        for (int nt = 0; nt < 2; nt++)
            #pragma unroll
            for (int r = 0; r < 4; r++)
                sm.ep[(ct * 16 + q * 4 + r) * 132 + w * 32 + nt * 16 + l15] = acc[ct][nt][r];
    __syncthreads();
    float* dst = ms ? part_b : out_b;
    int rr = t >> 3, cc = (t & 7) * 16;
    #pragma unroll
    for (int half = 0; half < 2; half++) {
        int row = rr + half * 32;
        const float4* srcv = (const float4*)&sm.ep[row * 132 + cc];
        float4* d = (float4*)&dst[(size_t)(c0 + row) * NT + n0 + cc];
        d[0] = srcv[0]; d[1] = srcv[1]; d[2] = srcv[2]; d[3] = srcv[3];
    }
}

// ---------------- out += partial ----------------
__global__ __launch_bounds__(256) void k_reduce(
    float* __restrict__ out, const float* __restrict__ part, int n4)
{
    int i = blockIdx.x * 256 + threadIdx.x, stride = gridDim.x * 256;
    float4* o4 = (float4*)out;
    const float4* p4 = (const float4*)part;
    for (int j = i; j < n4; j += stride) {
        float4 a = o4[j], b = p4[j];
        o4[j] = make_float4(a.x + b.x, a.y + b.y, a.z + b.z, a.w + b.w);
    }
}

extern "C" void kernel_launch(void* const* d_in, const int* in_sizes, int n_in,
                              void* d_out, int out_size, void* d_ws, size_t ws_size,
                              hipStream_t stream)
{
    const float* x1 = (const float*)d_in[0];
    const float* x2 = (const float*)d_in[1];
    const float* Wb = (const float*)d_in[2];
    const float* bb = (const float*)d_in[3];
    const float* Wc = (const float*)d_in[4];
    const float* bc = (const float*)d_in[5];
    const float* Wd = (const float*)d_in[6];
    const float* bd = (const float*)d_in[7];
    const float* alpha = (const float*)d_in[8];
    const float* beta  = (const float*)d_in[9];
    float* out = (float*)d_out;

    // ws layout (u16 units), total ~64.2 MB (r7-proven size):
    u16* ws  = (u16*)d_ws;
    u16* yab1 = ws;                             // [2][4096][128]  1,048,576
    u16* yab2 = ws + 1048576;                   //                 1,048,576
    u16* ft   = ws + 2097152;                   // [2][512][4096]  4,194,304
    u16* W1   = ws + 6291456;                   // [640][512]        327,680
    u16* W2f  = ws + 6619136;                   // [512][512]        262,144
    float* denom = (float*)(ws + 6881280);      // [2][2][4096] f32   32,768
    u16* P    = ws + 6914048;                   // [4096][4096]   16,777,216 (one batch)
    u16* x1T  = P;                              // overlay: dead before P written
    u16* x2T  = P + 4194304;
    float* partial = (float*)(ws + 23691264);   // [2][512][4096] f32  8,388,608

    hipMemsetAsync(denom, 0, (size_t)2 * NB * NT * sizeof(float), stream);
    k_convW<<<1152, 256, 0, stream>>>(Wb, Wc, Wd, alpha, beta, W1, W2f);
    k_prep<<<dim3(8, 64, 4), 256, 0, stream>>>(x1, x2, x1T, x2T);
    k_gemm<1><<<dim3(32, 5, 2), 256, 0, stream>>>(W1, W2f, x1T, bb, bc, bd, alpha, beta, yab1, ft);
    k_gemm<2><<<dim3(32, 5, 2), 256, 0, stream>>>(W1, W2f, x2T, bb, bc, bd, alpha, beta, yab2, ft);
    k_denom<<<2048, 256, 0, stream>>>(yab1, yab2, denom);
    for (int b = 0; b < NB; b++) {
        k_pmat<<<1024, 256, 0, stream>>>(
            yab1 + (size_t)b * NT * 128, yab2 + (size_t)b * NT * 128,
            denom + (size_t)b * NT, denom + (size_t)(NB + b) * NT, P);
        k_apply<<<512, 256, 0, stream>>>(
            P, ft + (size_t)b * CDIM * NT,
            out + (size_t)b * CDIM * NT, partial + (size_t)b * CDIM * NT);
    }
    k_reduce<<<2048, 256, 0, stream>>>(out, partial, NB * CDIM * NT / 4);
}